// Round 4
// baseline (585.571 us; speedup 1.0000x reference)
//
#include <hip/hip_runtime.h>

// Link_Embedding: out[e] = concat(X[src[e]], X[dst[e]])
// X: 100000 x 128 fp32 (51.2 MB), idx: 320000 x 2 int32, out: 320000 x 256 fp32 (327.7 MB).
//
// R7 = R6 resubmitted verbatim (GPU-acquisition timeout; the inversion has
// never been measured -- keep the A/B vs 385 us clean).
//
// R6: INVERT the data movement. R4/R5 showed the random-GATHER path is
// throughput-capped (~0.85 TB/s read): UNROLL 4->8 + scalar idx = NEUTRAL
// (380->385us), so not issue/MLP-bound. X (51.2MB) misses the 4MB/XCD L2s and
// the 327MB write stream fights the reads in L3/HBM. Harness memset proves the
// WRITE path alone does 6.4 TB/s.
//
// New scheme: bin the 640K (node, edge-slot) endpoints into 64-node buckets
// (32KB X-slices), then emit bucket-by-bucket:
//   - X is read streaming-once (51MB HBM) with 6.4x reuse from L1/L2
//   - randomness moves to the write side: 512B contiguous segments,
//     fire-and-forget (no miss-latency chain)
// Pipeline: K0 zero -> K1 histogram -> K2 scan (1 block) -> K3 scatter ->
// K4 emit. Workspace 5.14MB; falls back to the R5 gather kernel if ws too small.

typedef float f4 __attribute__((ext_vector_type(4)));

#define N_EDGES   320000
#define N_NODES   100000
#define F4_PER_ROW 32
#define BSHIFT    6
#define NB        1563            // ceil(100000 / 64) buckets
#define NENT      (2 * N_EDGES)   // 640000 endpoints

// Workspace layout (bytes)
#define OFF_OFF   0               // int[NB+1]  bucket offsets (also histogram)
#define CUR_OFF   8192            // int[NB]    scatter cursors
#define ENT_OFF   16384           // int2[NENT] (node, 2*edge+side)
#define WS_NEED   (ENT_OFF + (size_t)NENT * 8)

// ---------------- binned pipeline ----------------

__global__ void k0_zero(int* __restrict__ off) {
    const int i = blockIdx.x * 256 + threadIdx.x;
    if (i <= NB) off[i] = 0;
}

__global__ void k1_hist(const int2* __restrict__ idx, int* __restrict__ off) {
    const int e = blockIdx.x * 256 + threadIdx.x;   // grid covers N_EDGES exactly
    const int2 p = idx[e];
    atomicAdd(&off[p.x >> BSHIFT], 1);
    atomicAdd(&off[p.y >> BSHIFT], 1);
}

// Single-block exclusive scan of NB counters; writes offsets (off) and a
// cursor copy (cur). off[NB] = NENT.
__global__ void k2_scan(int* __restrict__ off, int* __restrict__ cur) {
    __shared__ int c[NB];
    for (int i = threadIdx.x; i < NB; i += 256) c[i] = off[i];
    __syncthreads();
    if (threadIdx.x < 64) {
        const int lane = threadIdx.x;
        const int lo = lane * 25;
        const int hi = (lo + 25 < NB) ? lo + 25 : NB;  // ceil(1563/64)=25
        int run = 0;
        for (int j = lo; j < hi; ++j) { const int t = c[j]; c[j] = run; run += t; }
        int inc = run;
        #pragma unroll
        for (int d = 1; d < 64; d <<= 1) {
            const int o = __shfl_up(inc, d, 64);
            if (lane >= d) inc += o;
        }
        const int exc = inc - run;      // exclusive prefix of this lane's chunk
        for (int j = lo; j < hi; ++j) c[j] += exc;
        if (lane == 63) off[NB] = inc;  // total = NENT
    }
    __syncthreads();
    for (int i = threadIdx.x; i < NB; i += 256) { off[i] = c[i]; cur[i] = c[i]; }
}

__global__ void k3_scatter(const int2* __restrict__ idx, int* __restrict__ cur,
                           int2* __restrict__ ent) {
    const int e = blockIdx.x * 256 + threadIdx.x;
    const int2 p = idx[e];
    const int a = atomicAdd(&cur[p.x >> BSHIFT], 1);
    ent[a] = make_int2(p.x, 2 * e);
    const int b = atomicAdd(&cur[p.y >> BSHIFT], 1);
    ent[b] = make_int2(p.y, 2 * e + 1);
}

// One block per bucket: the bucket's 32KB X-slice goes L1/L2-hot; each
// half-wave (32 lanes) moves one 512B row to its out slot.
__global__ __launch_bounds__(256) void k4_emit(
    const f4* __restrict__ X, const int* __restrict__ off,
    const int2* __restrict__ ent, f4* __restrict__ out)
{
    const int b    = blockIdx.x;
    const int lane = threadIdx.x & 63;
    const int wave = threadIdx.x >> 6;
    const int half = lane >> 5;
    const int col  = lane & 31;
    const int start = off[b];
    const int end   = off[b + 1];
    for (int i = start + wave * 2 + half; i < end; i += 8) {
        const int2 en = ent[i];                 // (node, 2*edge+side)
        const f4 v = X[(en.x << 5) + col];      // L1/L2-hot slice
        __builtin_nontemporal_store(
            v, &out[(en.y >> 1) * 64 + ((en.y & 1) << 5) + col]);
    }
}

// ---------------- fallback: R5 direct gather ----------------

#define BLOCK 256
#define UNROLL 8
#define EDGES_PER_BLOCK 32
#define GRID_G 10000

__global__ __launch_bounds__(BLOCK) void link_embed_gather(
    const f4* __restrict__ X, const int* __restrict__ idx, f4* __restrict__ out)
{
    const int lane = threadIdx.x & 63;
    const int wave = __builtin_amdgcn_readfirstlane((int)(threadIdx.x >> 6));
    const int ebase = blockIdx.x * EDGES_PER_BLOCK + wave * UNROLL;

    int2 p[UNROLL];
    const int2* __restrict__ ip = (const int2*)idx + ebase;
    #pragma unroll
    for (int k = 0; k < UNROLL; ++k) p[k] = ip[k];

    const int which = lane >> 5;
    const int col   = lane & 31;

    f4 v[UNROLL];
    #pragma unroll
    for (int k = 0; k < UNROLL; ++k) {
        const int row = which ? p[k].y : p[k].x;
        v[k] = X[(long long)row * F4_PER_ROW + col];
    }

    f4* __restrict__ ob = out + (long long)ebase * 64 + lane;
    #pragma unroll
    for (int k = 0; k < UNROLL; ++k)
        __builtin_nontemporal_store(v[k], ob + (long long)k * 64);
}

// ---------------- host ----------------

extern "C" void kernel_launch(void* const* d_in, const int* in_sizes, int n_in,
                              void* d_out, int out_size, void* d_ws, size_t ws_size,
                              hipStream_t stream) {
    const f4*   X    = (const f4*)d_in[0];
    const int*  idx  = (const int*)d_in[1];
    const int2* idx2 = (const int2*)d_in[1];
    f4*         out  = (f4*)d_out;

    if (d_ws == nullptr || ws_size < WS_NEED) {
        link_embed_gather<<<GRID_G, BLOCK, 0, stream>>>(X, idx, out);
        return;
    }

    int*  off = (int*)((char*)d_ws + OFF_OFF);
    int*  cur = (int*)((char*)d_ws + CUR_OFF);
    int2* ent = (int2*)((char*)d_ws + ENT_OFF);

    k0_zero   <<<(NB + 256) / 256, 256, 0, stream>>>(off);
    k1_hist   <<<N_EDGES / 256, 256, 0, stream>>>(idx2, off);
    k2_scan   <<<1, 256, 0, stream>>>(off, cur);
    k3_scatter<<<N_EDGES / 256, 256, 0, stream>>>(idx2, cur, ent);
    k4_emit   <<<NB, 256, 0, stream>>>(X, off, ent, out);
}

// Round 5
// 454.378 us; speedup vs baseline: 1.2887x; 1.2887x over previous
//
#include <hip/hip_runtime.h>

// Link_Embedding: out[e] = concat(X[src[e]], X[dst[e]])
// X: 100000 x 128 fp32 (51.2 MB), idx: 320000 x 2 int32, out: 320000 x 256 fp32 (327.7 MB).
//
// R8: HYBRID. Measured decomposition (R5/R6 profiles; poison memset ~206us is
// inside the timed region -- no kernel dispatch of ours exceeded 203us):
//   - R5 gather kernel  ~180us: random-512B READS (L3)  ~1.9 TB/s  <- bound
//   - R6 emit kernel    ~310us: random-512B NT-WRITES   ~1.0 TB/s  <- worse
//   - streaming writes (memset): 6.4 TB/s
// R4 (MLP 4->8) was neutral => read side is L2-miss/MSHR-occupancy bound, not
// issue-bound. Read-MSHR and write paths are DIFFERENT resources; R5 saturates
// reads while writes idle at 30%. So: offload part of the output volume to the
// scatter-write path, CONCURRENTLY in one fused kernel.
//   edges [0, S):      binned emit  (streaming X reads, random 512B writes,
//                      NORMAL stores -> L2/L3 write-back reorder; emit output
//                      (109MB) + X (51MB) fit L3 together)
//   edges [S, 320000): R5 gather    (random reads, nt streaming writes)
// Emit blocks first in grid (long-running, start early); gather blocks fill.
// Prelude (hist/scan/scatter) runs on only 217.6K endpoints (~20us).
// Fallback to pure gather if workspace too small.

typedef float f4 __attribute__((ext_vector_type(4)));

#define N_EDGES   320000
#define N_NODES   100000
#define BSHIFT    6
#define NB        1563            // ceil(100000 / 64) buckets
#define S_EDGES   108800          // edges routed through scatter/emit path
#define G_EDGES   (N_EDGES - S_EDGES)   // 211200 via gather
#define NENT      (2 * S_EDGES)   // 217600 binned endpoints

// Gather-path geometry
#define BLOCK 256
#define UNROLL 8
#define EDGES_PER_BLOCK 32        // 256 threads * 8 f4 = 2048 slots = 32 edges
#define GATHER_BLOCKS (G_EDGES / EDGES_PER_BLOCK)   // 6600 exact
#define FUSED_BLOCKS (NB + GATHER_BLOCKS)           // emit blocks first

// Workspace layout (bytes)
#define OFF_OFF   0               // int[NB+1]
#define CUR_OFF   8192            // int[NB]
#define ENT_OFF   16384           // int2[NENT]
#define WS_NEED   (ENT_OFF + (size_t)NENT * 8)

// ---------------- prelude ----------------

__global__ void k0_zero(int* __restrict__ off) {
    const int i = blockIdx.x * 256 + threadIdx.x;
    if (i <= NB) off[i] = 0;
}

__global__ void k1_hist(const int2* __restrict__ idx, int* __restrict__ off) {
    const int e = blockIdx.x * 256 + threadIdx.x;   // grid covers S_EDGES exactly
    const int2 p = idx[e];
    atomicAdd(&off[p.x >> BSHIFT], 1);
    atomicAdd(&off[p.y >> BSHIFT], 1);
}

__global__ void k2_scan(int* __restrict__ off, int* __restrict__ cur) {
    __shared__ int c[NB];
    for (int i = threadIdx.x; i < NB; i += 256) c[i] = off[i];
    __syncthreads();
    if (threadIdx.x < 64) {
        const int lane = threadIdx.x;
        const int lo = lane * 25;
        const int hi = (lo + 25 < NB) ? lo + 25 : NB;  // ceil(1563/64)=25
        int run = 0;
        for (int j = lo; j < hi; ++j) { const int t = c[j]; c[j] = run; run += t; }
        int inc = run;
        #pragma unroll
        for (int d = 1; d < 64; d <<= 1) {
            const int o = __shfl_up(inc, d, 64);
            if (lane >= d) inc += o;
        }
        const int exc = inc - run;
        for (int j = lo; j < hi; ++j) c[j] += exc;
        if (lane == 63) off[NB] = inc;  // = NENT
    }
    __syncthreads();
    for (int i = threadIdx.x; i < NB; i += 256) { off[i] = c[i]; cur[i] = c[i]; }
}

__global__ void k3_scatter(const int2* __restrict__ idx, int* __restrict__ cur,
                           int2* __restrict__ ent) {
    const int e = blockIdx.x * 256 + threadIdx.x;   // grid covers S_EDGES exactly
    const int2 p = idx[e];
    const int a = atomicAdd(&cur[p.x >> BSHIFT], 1);
    ent[a] = make_int2(p.x, 2 * e);
    const int b = atomicAdd(&cur[p.y >> BSHIFT], 1);
    ent[b] = make_int2(p.y, 2 * e + 1);
}

// ---------------- fused: emit blocks [0,NB) + gather blocks [NB,...) --------

__global__ __launch_bounds__(BLOCK) void k4_fused(
    const f4* __restrict__ X, const int* __restrict__ off,
    const int2* __restrict__ ent, const int* __restrict__ idx,
    f4* __restrict__ out)
{
    if (blockIdx.x < NB) {
        // ---- emit path: one block per 64-node bucket (32KB L1-hot slice) ----
        const int b    = blockIdx.x;
        const int lane = threadIdx.x & 63;
        const int wave = threadIdx.x >> 6;
        const int half = lane >> 5;
        const int col  = lane & 31;
        const int start = off[b];
        const int end   = off[b + 1];
        for (int i = start + wave * 2 + half; i < end; i += 8) {
            const int2 en = ent[i];             // (node, 2*e+side)
            const f4 v = X[(en.x << 5) + col];
            // NORMAL store: let L2/L3 write-back give the MC a reorder window.
            out[(long long)(en.y >> 1) * 64 + ((en.y & 1) << 5) + col] = v;
        }
    } else {
        // ---- gather path: edges [S_EDGES, N_EDGES), R5 structure ----
        const int gb   = blockIdx.x - NB;
        const int lane = threadIdx.x & 63;
        const int wave = __builtin_amdgcn_readfirstlane((int)(threadIdx.x >> 6));
        const int ebase = S_EDGES + gb * EDGES_PER_BLOCK + wave * UNROLL;

        int2 p[UNROLL];
        const int2* __restrict__ ip = (const int2*)idx + ebase;
        #pragma unroll
        for (int k = 0; k < UNROLL; ++k) p[k] = ip[k];

        const int which = lane >> 5;
        const int col   = lane & 31;

        f4 v[UNROLL];
        #pragma unroll
        for (int k = 0; k < UNROLL; ++k) {
            const int row = which ? p[k].y : p[k].x;
            v[k] = X[(long long)row * 32 + col];
        }

        f4* __restrict__ ob = out + (long long)ebase * 64 + lane;
        #pragma unroll
        for (int k = 0; k < UNROLL; ++k)
            __builtin_nontemporal_store(v[k], ob + (long long)k * 64);
    }
}

// ---------------- fallback: pure gather over all edges ----------------

__global__ __launch_bounds__(BLOCK) void link_embed_gather(
    const f4* __restrict__ X, const int* __restrict__ idx, f4* __restrict__ out)
{
    const int lane = threadIdx.x & 63;
    const int wave = __builtin_amdgcn_readfirstlane((int)(threadIdx.x >> 6));
    const int ebase = blockIdx.x * EDGES_PER_BLOCK + wave * UNROLL;

    int2 p[UNROLL];
    const int2* __restrict__ ip = (const int2*)idx + ebase;
    #pragma unroll
    for (int k = 0; k < UNROLL; ++k) p[k] = ip[k];

    const int which = lane >> 5;
    const int col   = lane & 31;

    f4 v[UNROLL];
    #pragma unroll
    for (int k = 0; k < UNROLL; ++k) {
        const int row = which ? p[k].y : p[k].x;
        v[k] = X[(long long)row * 32 + col];
    }

    f4* __restrict__ ob = out + (long long)ebase * 64 + lane;
    #pragma unroll
    for (int k = 0; k < UNROLL; ++k)
        __builtin_nontemporal_store(v[k], ob + (long long)k * 64);
}

// ---------------- host ----------------

extern "C" void kernel_launch(void* const* d_in, const int* in_sizes, int n_in,
                              void* d_out, int out_size, void* d_ws, size_t ws_size,
                              hipStream_t stream) {
    const f4*   X    = (const f4*)d_in[0];
    const int*  idx  = (const int*)d_in[1];
    const int2* idx2 = (const int2*)d_in[1];
    f4*         out  = (f4*)d_out;

    if (d_ws == nullptr || ws_size < WS_NEED) {
        link_embed_gather<<<N_EDGES / EDGES_PER_BLOCK, BLOCK, 0, stream>>>(X, idx, out);
        return;
    }

    int*  off = (int*)((char*)d_ws + OFF_OFF);
    int*  cur = (int*)((char*)d_ws + CUR_OFF);
    int2* ent = (int2*)((char*)d_ws + ENT_OFF);

    k0_zero   <<<(NB + 256) / 256, 256, 0, stream>>>(off);
    k1_hist   <<<S_EDGES / 256, 256, 0, stream>>>(idx2, off);   // 425 exact
    k2_scan   <<<1, 256, 0, stream>>>(off, cur);
    k3_scatter<<<S_EDGES / 256, 256, 0, stream>>>(idx2, cur, ent);
    k4_fused  <<<FUSED_BLOCKS, BLOCK, 0, stream>>>(X, off, ent, idx, out);
}